// Round 12
// baseline (2995.322 us; speedup 1.0000x reference)
//
#include <hip/hip_runtime.h>
#include <hip/hip_fp16.h>

#define S 31
#define D 14
#define H 50
#define NB 16384
#define NITER 48
#define LAMR 1e-4f
#define TSC 2.8853900817779268f   // 2*log2(e), folded into W at prep

// ws float-index layout
#define WS_D2   0      // 48: global sum ||F-X||^2 per iter
#define WS_F2   64     // 48: global sum ||F||^2 per iter
#define WS_WC1  128    // [64 n][32 k] f16 (1024 dw): rows n=h: [Wh|Wx|bhx|0]*TSC
#define WS_WOC  1152   // [16 d][64 k] f16 (512 dw): k<50 Wo*TSC, k50 bo*TSC, else 0
#define WS_WF   1664   // [32 s][16 d] f16 (256 dw), unscaled
#define WS_OUTK 4096   // 48*NB floats

typedef _Float16 f16x2 __attribute__((ext_vector_type(2)));
typedef _Float16 f16x4 __attribute__((ext_vector_type(4)));
typedef _Float16 f16x8 __attribute__((ext_vector_type(8)));
typedef float    f32x4 __attribute__((ext_vector_type(4)));

#if defined(__has_builtin) && __has_builtin(__builtin_amdgcn_rcpf)
#define FRCP(x) __builtin_amdgcn_rcpf(x)
#else
#define FRCP(x) (1.0f/(x))
#endif

#if defined(__has_builtin) && __has_builtin(__builtin_amdgcn_exp2f)
#define FEXP2(x) __builtin_amdgcn_exp2f(x)
#else
#define FEXP2(x) exp2f(x)
#endif

#define FDOT2(a,b,c) __builtin_amdgcn_fdot2((a),(b),(c),false)
#define F2I(v) __builtin_bit_cast(int,(v))
#define I2F(v) __builtin_bit_cast(float,(v))

__device__ __forceinline__ f16x2 pkrtz(float a, float b){
  auto r = __builtin_amdgcn_cvt_pkrtz(a, b);
  return __builtin_bit_cast(f16x2, r);
}

template<int CTRL>
__device__ __forceinline__ float dppadd(float v){
  int pv = __builtin_amdgcn_update_dpp(0, __builtin_bit_cast(int, v),
                                       CTRL, 0xF, 0xF, true);
  return v + __builtin_bit_cast(float, pv);
}

// triangular index, i<=j, 6x6
#define AIJ(i,j) ((i)*6 - ((i)*((i)+1))/2 + (j))

__device__ __forceinline__ float tfast(float x){
  // weights pre-scaled by 2*log2e: tanh(pre) = 1 - 2/(exp2(x)+1)
  float e = FEXP2(x);
  return 1.f - 2.f * FRCP(e + 1.f);
}

__global__ void prep_kernel(const float* __restrict__ Wh, const float* __restrict__ bh,
                            const float* __restrict__ Wx, const float* __restrict__ bx,
                            const float* __restrict__ Wo, const float* __restrict__ bo,
                            const float* __restrict__ Wf, float* __restrict__ ws){
  int t = threadIdx.x;                       // 1 block x 256
  for (int i=t;i<128;i+=256) ws[i]=0.f;      // zero norm accumulators
  // Wcomb1: rows n=h (0..63), k-major: [Wh(0..13)|Wx(14..27)|bhx(28)|0]
  __half2* wc1 = (__half2*)(ws + WS_WC1);
  for (int i=t;i<1024;i+=256){
    int n=i>>4, kp=i&15, k0=2*kp, k1=2*kp+1;
    float v0=0.f, v1=0.f;
    if (n<H){
      v0 = (k0<14)? Wh[n*D+k0]*TSC : (k0<28)? Wx[n*D+(k0-14)]*TSC : (k0==28)? (bh[n]+bx[n])*TSC : 0.f;
      v1 = (k1<14)? Wh[n*D+k1]*TSC : (k1<28)? Wx[n*D+(k1-14)]*TSC : (k1==28)? (bh[n]+bx[n])*TSC : 0.f;
    }
    wc1[i] = __floats2half2_rn(v0,v1);
  }
  // WoCmb: rows m=d (0..15), k-major over h: Wo (k<50), bo at k=50
  __half2* woc = (__half2*)(ws + WS_WOC);
  for (int i=t;i<512;i+=256){
    int d=i>>5, kp=i&31, k0=2*kp, k1=2*kp+1;
    float v0=0.f, v1=0.f;
    if (d<D){
      v0 = (k0<H)? Wo[d*H+k0]*TSC : (k0==H)? bo[d]*TSC : 0.f;
      v1 = (k1<H)? Wo[d*H+k1]*TSC : (k1==H)? bo[d]*TSC : 0.f;
    }
    woc[i] = __floats2half2_rn(v0,v1);
  }
  __half2* wf = (__half2*)(ws + WS_WF);      // [32 s][16 d]
  for (int i=t;i<256;i+=256){
    int s=i>>3, dp=i&7, d0=2*dp, d1=2*dp+1;
    float v0=(s<S&&d0<D)?Wf[s*D+d0]:0.f, v1=(s<S&&d1<D)?Wf[s*D+d1]:0.f;
    wf[i] = __floats2half2_rn(v0,v1);
  }
}

// One wave per block. 2 elems/wave: token rows 0-31 = elem A, 32-63 = elem B.
// AZ buffer ELIMINATED: L1 B-frags built in registers from invariant x-part
// (binv) + per-iteration z patches shuffled from xo owner lanes (bpermute,
// bit-identical values to the old AZ staging). HB keeps the H round trip.
#define HBS 144
__global__ __launch_bounds__(64, 2)
void solver_kernel(const float* __restrict__ x,
                   const f16x8* __restrict__ wc1, const f16x8* __restrict__ woc,
                   const f16x2* __restrict__ wf,
                   float* __restrict__ outk, float* __restrict__ d2p, float* __restrict__ f2p){
  const int l = threadIdx.x;
  const int a = l & 15;
  const int g = l >> 4;
  const int elemA = blockIdx.x*2;

  __shared__ __align__(16) unsigned char HB[64*HBS];  // 9216B; prologue reuse: [64 tok][48B x-stage]

  // ---- prologue: stage x rows (48B, zero-padded) into HB
#pragma unroll
  for (int i=0;i<12;++i) *(float*)(HB + l*48 + i*4) = 0.f;
  {
    int s = l & 31, e = l >> 5;
    if (s < S){
      const float* xr = x + ((size_t)(elemA+e)*S + s)*D;
#pragma unroll
      for (int i=0;i<7;++i){
        __half2 h2 = __floats2half2_rn(xr[2*i], xr[2*i+1]);
        *(f16x2*)(HB + l*48 + i*4) = __builtin_bit_cast(f16x2, h2);
      }
    }
  }
  // invariant B-frag parts: g=0: x dims 0-7; g=1: x 8-13 (+z slot); g=2: all z;
  // g=3: zeros + k28=1.0 constant. (g>=2 read the zero pad region.)
  int4 binv[4];
  {
    int off = (g<3 ? g : 2)*16;
#pragma unroll
    for (int nt=0;nt<4;++nt){
      int4 v = *(const int4*)(HB + (nt*16+a)*48 + off);
      if (g==3) v.z = 0x00003C00;     // (k28,k29) = (1.0h, 0)
      binv[nt] = v;
    }
  }
  // loop-invariant weight fragments in registers
  const f16x8 wc1f0 = wc1[( 0+a)*4 + g], wc1f1 = wc1[(16+a)*4 + g];
  const f16x8 wc1f2 = wc1[(32+a)*4 + g], wc1f3 = wc1[(48+a)*4 + g];
  const f16x8 wA0 = woc[a*8 + g], wA1 = woc[a*8 + 4 + g];
  const f16x2 wfr0 = wf[a*8+g*2],      wfr1 = wf[a*8+g*2+1];
  const f16x2 wfr2 = wf[(16+a)*8+g*2], wfr3 = wf[(16+a)*8+g*2+1];

  const f16x2 zz = {(_Float16)0.f,(_Float16)0.f};

  // history [6 slots][8 = nt*2+w] + current X (xo) in C-layout registers
  f16x2 Fh[48], Gh[48], fo[8], xo[8];
  float GG[21];
#pragma unroll
  for (int i=0;i<48;++i){ Fh[i]=zz; Gh[i]=zz; }
#pragma unroll
  for (int i=0;i<8;++i) xo[i]=zz;
#pragma unroll
  for (int i=0;i<21;++i) GG[i]=0.f;

#pragma unroll 1
  for (int kk=0; kk<50; ++kk){
    if (kk >= 2){
      float A_[21], yv[6];
      if (kk >= 6){
#pragma unroll
        for (int i=0;i<6;++i)
#pragma unroll
          for (int j=i;j<6;++j) A_[AIJ(i,j)] = GG[AIJ(i,j)] + ((i==j)?LAMR:0.f);
      } else {
        int lo = 6-kk;
#pragma unroll
        for (int i=0;i<6;++i)
#pragma unroll
          for (int j=i;j<6;++j){
            float v = GG[AIJ(i,j)] + ((i==j)?LAMR:0.f);
            A_[AIJ(i,j)] = (i>=lo)? v : ((i==j)?1e30f:0.f);
          }
      }
#pragma unroll
      for (int i=0;i<6;++i) yv[i]=1.f;
#pragma unroll
      for (int p=0;p<6;++p){
        float ip = FRCP(A_[AIJ(p,p)]);
        A_[AIJ(p,p)] = ip;
#pragma unroll
        for (int i=p+1;i<6;++i){
          float m = A_[AIJ(p,i)]*ip;
#pragma unroll
          for (int j=i;j<6;++j) A_[AIJ(i,j)] -= m*A_[AIJ(p,j)];
          yv[i] -= m*yv[p];
        }
      }
#pragma unroll
      for (int p=5;p>=0;--p){
        float acc=yv[p];
#pragma unroll
        for (int j=p+1;j<6;++j) acc -= A_[AIJ(p,j)]*yv[j];
        yv[p]=acc*A_[AIJ(p,p)];
      }
      float isum = FRCP(yv[0]+yv[1]+yv[2]+yv[3]+yv[4]+yv[5]);
      // Xk = sum_j alpha_j F_j ; alphas per elem (half-wave solves), exchanged
#pragma unroll
      for (int i=0;i<8;++i) xo[i]=zz;
#pragma unroll
      for (int j=0;j<6;++j){
        float ao = yv[j]*isum;
        float ot = __shfl_xor(ao, 32);
        float vA = (l<32)? ao : ot;
        float vB = (l<32)? ot : ao;
        _Float16 hA=(_Float16)vA, hB=(_Float16)vB;
        f16x2 a2A={hA,hA}, a2B={hB,hB};
#pragma unroll
        for (int i=0;i<4;++i) xo[i] += a2A*Fh[j*8+i];
#pragma unroll
        for (int i=4;i<8;++i) xo[i] += a2B*Fh[j*8+i];
      }
    } else if (kk == 1){
#pragma unroll
      for (int i=0;i<8;++i) xo[i]=fo[i];    // X1 = F0
    }
    // ---- build L1 B-frags in registers (z patches via bpermute from xo)
    f16x8 bz[4];
    {
      float xof[8];
#pragma unroll
      for (int i=0;i<8;++i) xof[i] = __builtin_bit_cast(float, xo[i]);
#pragma unroll
      for (int nt=0;nt<4;++nt){
        float t01 = __shfl(xof[nt*2],   a);       // g0: z dims 0,1
        float t02 = __shfl(xof[nt*2+1], a);       // g0: z dims 2,3
        float t12a= __shfl(xof[nt*2],   a+16);    // g1: z dims 4,5
        float t12b= __shfl(xof[nt*2+1], a+16);    // g1: z dims 6,7
        float t23 = __shfl(xof[nt*2+1], a+32);    // g2: z dims 10,11
        int4 bv = binv[nt];
        float dw0 = (g==2)? t02  : (g==3)? t23        : I2F(bv.x);
        float dw1 = (g==2)? t12a : (g==3)? xof[nt*2]  : I2F(bv.y);
        float dw2 = (g==2)? t12b :                      I2F(bv.z);
        float dw3 = (g==1)? t01  : (g==2)? xof[nt*2]  : I2F(bv.w);
        int4 bi = { F2I(dw0), F2I(dw1), F2I(dw2), F2I(dw3) };
        bz[nt] = __builtin_bit_cast(f16x8, bi);
      }
    }
    // ---- L1: H = tanh(Wc1·[x|z|1]^T) -> HB[tok][h], b64 packed writes
#pragma unroll
    for (int nt=0;nt<4;++nt){
#pragma unroll
      for (int mt=0;mt<4;++mt){
        f32x4 c = {0.f,0.f,0.f,0.f};
        f16x8 A = (mt==0)? wc1f0 : (mt==1)? wc1f1 : (mt==2)? wc1f2 : wc1f3;
        c = __builtin_amdgcn_mfma_f32_16x16x32_f16(A, bz[nt], c, 0,0,0);
        f16x4 hv;
#pragma unroll
        for (int q=0;q<4;++q){
          _Float16 t = (_Float16)tfast(c[q]);
          if (mt==3 && g==0 && q==2) t = (_Float16)1.0f;   // h==50: bo column
          hv[q] = t;
        }
        *(f16x4*)(HB + (nt*16+a)*HBS + mt*32 + g*8) = hv;
      }
    }
    // ---- L2: F = tanh(Wo·H^T) ; lane gets F[d=g*4+q][tok=nt*16+a]
#pragma unroll
    for (int nt=0;nt<4;++nt){
      int r2 = nt*16 + a;
      f16x8 b0 = *(const f16x8*)(HB + r2*HBS +  0 + g*16);
      f16x8 b1 = *(const f16x8*)(HB + r2*HBS + 64 + g*16);
      f32x4 c = {0.f,0.f,0.f,0.f};
      c = __builtin_amdgcn_mfma_f32_16x16x32_f16(wA0, b0, c, 0,0,0);
      c = __builtin_amdgcn_mfma_f32_16x16x32_f16(wA1, b1, c, 0,0,0);
      fo[nt*2]   = pkrtz(tfast(c[0]), tfast(c[1]));
      fo[nt*2+1] = pkrtz(tfast(c[2]), tfast(c[3]));
    }
    // ---- g = F - X (X directly from registers)
    f16x2 go[8];
#pragma unroll
    for (int i=0;i<8;++i) go[i] = fo[i] - xo[i];
    if (a == 15){  // s==31 rows (nt odd) are inactive
      fo[2]=zz; fo[3]=zz; fo[6]=zz; fo[7]=zz;
      go[2]=zz; go[3]=zz; go[6]=zz; go[7]=zz;
    }
    // ---- push: shift FIRST, then dots from history
#pragma unroll
    for (int j=0;j<5;++j)
#pragma unroll
      for (int i=0;i<8;++i){ Fh[j*8+i]=Fh[(j+1)*8+i]; Gh[j*8+i]=Gh[(j+1)*8+i]; }
#pragma unroll
    for (int i=0;i<8;++i){ Fh[40+i]=fo[i]; Gh[40+i]=go[i]; }
    float rv[16];   // [0..7]=elem A {dn0..4,d2,f2,po}, [8..15]=elem B
#pragma unroll
    for (int j=0;j<5;++j){
      float pa=0.f, pb=0.f;
#pragma unroll
      for (int i=0;i<4;++i) pa = FDOT2(Gh[40+i], Gh[j*8+i], pa);
#pragma unroll
      for (int i=4;i<8;++i) pb = FDOT2(Gh[40+i], Gh[j*8+i], pb);
      rv[j]=pa; rv[8+j]=pb;
    }
    {
      float pa=0.f,pb=0.f,qa=0.f,qb=0.f,ra=0.f,rb=0.f;
#pragma unroll
      for (int i=0;i<4;++i){
        pa = FDOT2(Gh[40+i], Gh[40+i], pa);
        qa = FDOT2(Fh[40+i], Fh[40+i], qa);
      }
#pragma unroll
      for (int i=4;i<8;++i){
        pb = FDOT2(Gh[40+i], Gh[40+i], pb);
        qb = FDOT2(Fh[40+i], Fh[40+i], qb);
      }
      ra = FDOT2(Fh[40+0], wfr0, ra); ra = FDOT2(Fh[40+1], wfr1, ra);
      ra = FDOT2(Fh[40+2], wfr2, ra); ra = FDOT2(Fh[40+3], wfr3, ra);
      rb = FDOT2(Fh[44+0], wfr0, rb); rb = FDOT2(Fh[44+1], wfr1, rb);
      rb = FDOT2(Fh[44+2], wfr2, rb); rb = FDOT2(Fh[44+3], wfr3, rb);
      rv[5]=pa; rv[13]=pb; rv[6]=qa; rv[14]=qb; rv[7]=ra; rv[15]=rb;
    }
#pragma unroll
    for (int i=0;i<16;++i) rv[i] = dppadd<0x121>(rv[i]);
#pragma unroll
    for (int i=0;i<16;++i) rv[i] = dppadd<0x122>(rv[i]);
#pragma unroll
    for (int i=0;i<16;++i) rv[i] = dppadd<0x124>(rv[i]);
#pragma unroll
    for (int i=0;i<16;++i) rv[i] = dppadd<0x128>(rv[i]);
#pragma unroll
    for (int i=0;i<16;++i) rv[i] += __shfl_xor(rv[i],16);
#pragma unroll
    for (int i=0;i<16;++i) rv[i] += __shfl_xor(rv[i],32);
    // GG update with own-elem values (lane<32 solves A, else B)
    const bool eB = (l >= 32);
#pragma unroll
    for (int i_=0;i_<5;++i_)
#pragma unroll
      for (int j_=i_;j_<5;++j_) GG[AIJ(i_,j_)] = GG[AIJ(i_+1,j_+1)];
#pragma unroll
    for (int j=0;j<5;++j) GG[AIJ(j,5)] = eB? rv[8+j] : rv[j];
    GG[AIJ(5,5)] = eB? rv[13] : rv[5];
    if (kk>=2 && l==0){
      atomicAdd(&d2p[kk-2], rv[5]+rv[13]);
      atomicAdd(&f2p[kk-2], rv[6]+rv[14]);
      outk[(size_t)(kk-2)*NB + elemA]     = rv[7];
      outk[(size_t)(kk-2)*NB + elemA + 1] = rv[15];
    }
  }
}

__global__ void final_kernel(const float* __restrict__ d2p, const float* __restrict__ f2p,
                             const float* __restrict__ outk, const float* __restrict__ bf,
                             float* __restrict__ out){
  int b = blockIdx.x*blockDim.x + threadIdx.x;
  float best = 1e8f; int kst = 0;
  for (int k=0;k<NITER;++k){
    float rel = sqrtf(d2p[k]) / (1e-5f + sqrtf(f2p[k]));
    if (rel < best){ best = rel; kst = k; }
  }
  out[b] = outk[(size_t)kst*NB + b] + bf[0];
}

extern "C" void kernel_launch(void* const* d_in, const int* in_sizes, int n_in,
                              void* d_out, int out_size, void* d_ws, size_t ws_size,
                              hipStream_t stream){
  const float* x  = (const float*)d_in[0];
  const float* Wh = (const float*)d_in[1];
  const float* bh = (const float*)d_in[2];
  const float* Wx = (const float*)d_in[3];
  const float* bx = (const float*)d_in[4];
  const float* Wo = (const float*)d_in[5];
  const float* bo = (const float*)d_in[6];
  const float* Wf = (const float*)d_in[7];
  const float* bf = (const float*)d_in[8];
  float* ws  = (float*)d_ws;
  float* out = (float*)d_out;

  hipLaunchKernelGGL(prep_kernel, dim3(1), dim3(256), 0, stream, Wh,bh,Wx,bx,Wo,bo,Wf,ws);
  hipLaunchKernelGGL(solver_kernel, dim3(NB/2), dim3(64), 0, stream,
                     x, (const f16x8*)(ws+WS_WC1), (const f16x8*)(ws+WS_WOC),
                     (const f16x2*)(ws+WS_WF),
                     ws+WS_OUTK, ws+WS_D2, ws+WS_F2);
  hipLaunchKernelGGL(final_kernel, dim3(NB/256), dim3(256), 0, stream,
                     ws+WS_D2, ws+WS_F2, ws+WS_OUTK, bf, out);
}

// Round 14
// 2814.904 us; speedup vs baseline: 1.0641x; 1.0641x over previous
//
#include <hip/hip_runtime.h>
#include <hip/hip_fp16.h>

#define S 31
#define D 14
#define H 50
#define NB 16384
#define NITER 48
#define LAMR 1e-4f
#define TSC 2.8853900817779268f   // 2*log2(e), folded into weights at prep

// ws float-index layout
#define WS_D2   0      // 48: global sum ||F-X||^2 per iter
#define WS_F2   64     // 48: global sum ||F||^2 per iter
#define WS_WHP  128    // 50x16 fp32 Wh (padded, pre-scaled by TSC)
#define WS_BHX  928    // 64: (bh+bx)*TSC fp32
#define WS_BO   992    // 16: bo*TSC fp32
#define WS_WX2  1024   // 50x8 half2: Wx*TSC rows packed (d pairs)
#define WS_WO2  1424   // 14x26 half2: Wo*TSC rows packed (h pairs)
#define WS_WF2  1792   // 32x8 half2: Wf per-s slices (row 31 = 0), UNscaled
#define WS_OUTK 4096   // 48*NB floats

typedef _Float16 f16x2 __attribute__((ext_vector_type(2)));

#if defined(__has_builtin) && __has_builtin(__builtin_amdgcn_rcpf)
#define FRCP(x) __builtin_amdgcn_rcpf(x)
#else
#define FRCP(x) (1.0f/(x))
#endif

#if defined(__has_builtin) && __has_builtin(__builtin_amdgcn_exp2f)
#define FEXP2(x) __builtin_amdgcn_exp2f(x)
#else
#define FEXP2(x) exp2f(x)
#endif

#define FDOT2(a,b,c) __builtin_amdgcn_fdot2((a),(b),(c),false)

__device__ __forceinline__ f16x2 pkrtz(float a, float b){
  auto r = __builtin_amdgcn_cvt_pkrtz(a, b);
  return __builtin_bit_cast(f16x2, r);
}
#define PKRTZ(a,b) pkrtz((a),(b))

__device__ __forceinline__ f16x2 pack_rn(float a, float b){
  __half2 h = __floats2half2_rn(a, b);
  return __builtin_bit_cast(f16x2, h);
}

// DPP rotate-add within 16-lane rows: full-rate VALU, no LDS-pipe latency.
template<int CTRL>
__device__ __forceinline__ float dppadd(float v){
  int pv = __builtin_amdgcn_update_dpp(0, __builtin_bit_cast(int, v),
                                       CTRL, 0xF, 0xF, true);
  return v + __builtin_bit_cast(float, pv);
}

// triangular index, i<=j, 6x6
#define AIJ(i,j) ((i)*6 - ((i)*((i)+1))/2 + (j))

__device__ __forceinline__ float tfast(float x){
  // weights pre-scaled by 2*log2e: tanh(pre) = 1 - 2/(exp2(x)+1)
  float e = FEXP2(x);
  return 1.f - 2.f * FRCP(e + 1.f);
}

__global__ void prep_kernel(const float* __restrict__ Wh, const float* __restrict__ bh,
                            const float* __restrict__ Wx, const float* __restrict__ bx,
                            const float* __restrict__ Wo, const float* __restrict__ bo,
                            const float* __restrict__ Wf, float* __restrict__ ws){
  int t = threadIdx.x;                       // 1 block x 256
  for (int i=t;i<128;i+=256) ws[i]=0.f;      // zero norm accumulators
  for (int i=t;i<800;i+=256){
    int h=i>>4, d=i&15;
    ws[WS_WHP+i] = (d<D)? Wh[h*D+d]*TSC : 0.f;
  }
  for (int i=t;i<64;i+=256) ws[WS_BHX+i] = (i<H)? (bh[i]+bx[i])*TSC : 0.f;
  for (int i=t;i<16;i+=256) ws[WS_BO+i]  = (i<D)? bo[i]*TSC : 0.f;
  __half2* wx2 = (__half2*)(ws + WS_WX2);
  for (int i=t;i<400;i+=256){
    int h=i>>3, dd=i&7, d0=2*dd, d1=2*dd+1;
    float a=(d0<D)?Wx[h*D+d0]*TSC:0.f, b=(d1<D)?Wx[h*D+d1]*TSC:0.f;
    wx2[i] = __floats2half2_rn(a,b);
  }
  __half2* wo2 = (__half2*)(ws + WS_WO2);
  for (int i=t;i<364;i+=256){
    int d=i/26, hh=i-26*d, h0=2*hh, h1=2*hh+1;
    float a=(hh<25)?Wo[d*H+h0]*TSC:0.f, b=(hh<25)?Wo[d*H+h1]*TSC:0.f;
    wo2[i] = __floats2half2_rn(a,b);
  }
  __half2* wf2 = (__half2*)(ws + WS_WF2);
  for (int i=t;i<256;i+=256){
    int s=i>>3, dd=i&7, d0=2*dd, d1=2*dd+1;
    float a=(s<S && d0<D)?Wf[s*D+d0]:0.f, b=(s<S && d1<D)?Wf[s*D+d1]:0.f;
    wf2[i] = __floats2half2_rn(a,b);
  }
}

// f-eval, fused layers; weights via wave-uniform addresses (s_load/SGPR path).
#define FEVAL() do{ \
  float oacc_[14]; \
  _Pragma("unroll") for (int d_=0; d_<14; ++d_) oacc_[d_] = bop[d_]; \
  _Pragma("unroll") \
  for (int hh_=0; hh_<25; ++hh_){ \
    f16x2 hx2_ = hxr2[hh_]; \
    float a0_ = (float)hx2_[0], b0_ = (float)hx2_[1]; \
    _Pragma("unroll") for (int q_=0;q_<7;++q_){ \
      a0_ = FDOT2(xvh[q_], wx2[(2*hh_)*8+q_],   a0_); \
      b0_ = FDOT2(xvh[q_], wx2[(2*hh_+1)*8+q_], b0_); } \
    f16x2 th_ = PKRTZ(tfast(a0_), tfast(b0_)); \
    _Pragma("unroll") for (int d_=0; d_<14; ++d_) \
      oacc_[d_] = FDOT2(th_, wo2[d_*26+hh_], oacc_[d_]); \
  } \
  _Pragma("unroll") for (int dp_=0; dp_<7; ++dp_) \
    fvh[dp_] = PKRTZ(tfast(oacc_[2*dp_]), tfast(oacc_[2*dp_+1])); \
}while(0)

#define ZERO_INACT() do{ \
  if (!act){ \
    _Pragma("unroll") for (int q_=0;q_<7;++q_){ fvh[q_]=zzv; gvh[q_]=zzv; } \
  } \
}while(0)

// Shift-based history push (constant indices -> stays in regs).
// All 8 per-iteration 32-lane reductions batched; levels 1/2/4/8 via DPP
// row_ror (pure VALU), only the 16-level crosses rows via ds-shfl.
#define PUSHB(DOPROJ) do{ \
  float rv_[8]; \
  _Pragma("unroll") for (int j_=0;j_<5;++j_){ \
    float acc_=0.f; \
    _Pragma("unroll") for (int q_=0;q_<7;++q_) acc_ = FDOT2(gvh[q_], Gh[(j_+1)*7+q_], acc_); \
    rv_[j_] = acc_; } \
  d2l=0.f; f2l=0.f; \
  _Pragma("unroll") for (int q_=0;q_<7;++q_){ \
    d2l = FDOT2(gvh[q_], gvh[q_], d2l); \
    f2l = FDOT2(fvh[q_], fvh[q_], f2l); } \
  rv_[5]=d2l; rv_[6]=f2l; rv_[7]=0.f; \
  if (DOPROJ){ \
    float pa_=0.f; \
    _Pragma("unroll") for (int q_=0;q_<7;++q_) pa_ = FDOT2(fvh[q_], wfr[q_], pa_); \
    rv_[7]=pa_; } \
  _Pragma("unroll") for (int i_=0;i_<8;++i_) rv_[i_] = dppadd<0x121>(rv_[i_]); \
  _Pragma("unroll") for (int i_=0;i_<8;++i_) rv_[i_] = dppadd<0x122>(rv_[i_]); \
  _Pragma("unroll") for (int i_=0;i_<8;++i_) rv_[i_] = dppadd<0x124>(rv_[i_]); \
  _Pragma("unroll") for (int i_=0;i_<8;++i_) rv_[i_] = dppadd<0x128>(rv_[i_]); \
  _Pragma("unroll") for (int i_=0;i_<8;++i_) rv_[i_] += __shfl_xor(rv_[i_], 16); \
  d2r = rv_[5]; f2r = rv_[6]; po_red = rv_[7]; \
  _Pragma("unroll") for (int j_=0;j_<5;++j_) \
    _Pragma("unroll") for (int q_=0;q_<7;++q_){ \
      Fh[j_*7+q_] = Fh[(j_+1)*7+q_]; Gh[j_*7+q_] = Gh[(j_+1)*7+q_]; } \
  _Pragma("unroll") for (int q_=0;q_<7;++q_){ Fh[35+q_]=fvh[q_]; Gh[35+q_]=gvh[q_]; } \
  _Pragma("unroll") for (int i_=0;i_<5;++i_) \
    _Pragma("unroll") for (int j_=i_;j_<5;++j_) GG[AIJ(i_,j_)] = GG[AIJ(i_+1,j_+1)]; \
  _Pragma("unroll") for (int j_=0;j_<5;++j_) GG[AIJ(j_,5)] = rv_[j_]; \
  GG[AIJ(5,5)] = d2r; \
}while(0)

// One wave per block; no barriers.
__global__ __launch_bounds__(64, 3)
void solver_kernel(const float* __restrict__ x,
                   const float* __restrict__ whp, const float* __restrict__ bhx,
                   const float* __restrict__ bop,
                   const f16x2* __restrict__ wx2, const f16x2* __restrict__ wo2,
                   const f16x2* __restrict__ wf2,
                   float* __restrict__ outk, float* __restrict__ d2p, float* __restrict__ f2p){
  const int tid  = threadIdx.x;
  const int lane = tid & 63;
  const int s    = tid & 31;
  const int elem = blockIdx.x*2 + (tid>>5);
  const bool act = (s < S);

  // hx as f16x2, stride 27 words (odd -> all-bank spread)
  __shared__ f16x2 hx2_sh[64*27];           // 6912 B
  f16x2* hxw2 = hx2_sh + tid*27;

  { // prologue: hx[h] = (x_s . Wh_h + bh_h + bx_h)*TSC (scale via weights)
    float xd[D];
#pragma unroll
    for (int d=0; d<D; ++d) xd[d]=0.f;
    if (act){
      const float* xr = x + ((size_t)elem*S + s)*D;
#pragma unroll
      for (int d=0; d<D; ++d) xd[d]=xr[d];
    }
#pragma unroll 5
    for (int hp=0; hp<25; ++hp){
      float a0 = bhx[2*hp], a1 = bhx[2*hp+1];
#pragma unroll
      for (int d=0; d<D; ++d){
        a0 += xd[d]*whp[(2*hp)*16+d];
        a1 += xd[d]*whp[(2*hp+1)*16+d];
      }
      hxw2[hp] = pack_rn(a0, a1);
    }
  }
  const f16x2* hxr2 = hxw2;
  const f16x2 zzv = {(_Float16)0.f, (_Float16)0.f};
  const f16x2* wfr = wf2 + s*8;

  f16x2 Fh[42], Gh[42], xvh[7], fvh[7], gvh[7];
  float GG[21];
  float d2l, f2l, d2r, f2r, po_red;
#pragma unroll
  for (int i=0;i<42;++i){ Fh[i]=zzv; Gh[i]=zzv; }
#pragma unroll
  for (int i=0;i<21;++i) GG[i]=0.f;

  // init entry 0: X0=0, F0=f(0)
#pragma unroll
  for (int q=0;q<7;++q) xvh[q]=zzv;
  FEVAL();
#pragma unroll
  for (int q=0;q<7;++q) gvh[q]=fvh[q]-xvh[q];
  ZERO_INACT();
  PUSHB(0);
  // init entry 1: X1=F0, F1=f(F0)
#pragma unroll
  for (int q=0;q<7;++q) xvh[q]=fvh[q];
  FEVAL();
#pragma unroll
  for (int q=0;q<7;++q) gvh[q]=fvh[q]-xvh[q];
  ZERO_INACT();
  PUSHB(0);

#pragma unroll 1
  for (int kk=2; kk<50; ++kk){
    float A_[21], invd[6], yv[6];
    if (kk >= 6){
#pragma unroll
      for (int i=0;i<6;++i)
#pragma unroll
        for (int j=i;j<6;++j) A_[AIJ(i,j)] = GG[AIJ(i,j)] + ((i==j)?LAMR:0.f);
    } else {
      int lo = 6-kk;
#pragma unroll
      for (int i=0;i<6;++i)
#pragma unroll
        for (int j=i;j<6;++j){
          float v = GG[AIJ(i,j)] + ((i==j)?LAMR:0.f);
          A_[AIJ(i,j)] = (i>=lo)? v : ((i==j)?1e30f:0.f);
        }
    }
#pragma unroll
    for (int i=0;i<6;++i) yv[i]=1.f;
    // symmetric GE (no pivoting; SPD + big-diag pads)
#pragma unroll
    for (int p=0;p<6;++p){
      invd[p] = FRCP(A_[AIJ(p,p)]);
#pragma unroll
      for (int i=p+1;i<6;++i){
        float m = A_[AIJ(p,i)]*invd[p];
#pragma unroll
        for (int j=i;j<6;++j) A_[AIJ(i,j)] -= m*A_[AIJ(p,j)];
        yv[i] -= m*yv[p];
      }
    }
#pragma unroll
    for (int p=5;p>=0;--p){
      float acc=yv[p];
#pragma unroll
      for (int j=p+1;j<6;++j) acc -= A_[AIJ(p,j)]*yv[j];
      yv[p]=acc*invd[p];
    }
    float isum = FRCP(yv[0]+yv[1]+yv[2]+yv[3]+yv[4]+yv[5]);
    // Xk = sum_j alpha_j F_j  (fp16 packed)
#pragma unroll
    for (int q=0;q<7;++q) xvh[q]=zzv;
#pragma unroll
    for (int j=0;j<6;++j){
      _Float16 ah = (_Float16)(yv[j]*isum);
      f16x2 a2 = {ah, ah};
#pragma unroll
      for (int q=0;q<7;++q) xvh[q] += a2*Fh[j*7+q];
    }
    FEVAL();
#pragma unroll
    for (int q=0;q<7;++q) gvh[q]=fvh[q]-xvh[q];
    ZERO_INACT();
    PUSHB(1);
    float d2w = d2r + __shfl_xor(d2r, 32);
    float f2w = f2r + __shfl_xor(f2r, 32);
    if (lane==0){ atomicAdd(&d2p[kk-2], d2w); atomicAdd(&f2p[kk-2], f2w); }
    if (s==0) outk[(size_t)(kk-2)*NB + elem] = po_red;
  }
}

__global__ void final_kernel(const float* __restrict__ d2p, const float* __restrict__ f2p,
                             const float* __restrict__ outk, const float* __restrict__ bf,
                             float* __restrict__ out){
  int b = blockIdx.x*blockDim.x + threadIdx.x;
  float best = 1e8f; int kst = 0;
  for (int k=0;k<NITER;++k){
    float rel = sqrtf(d2p[k]) / (1e-5f + sqrtf(f2p[k]));
    if (rel < best){ best = rel; kst = k; }
  }
  out[b] = outk[(size_t)kst*NB + b] + bf[0];
}

extern "C" void kernel_launch(void* const* d_in, const int* in_sizes, int n_in,
                              void* d_out, int out_size, void* d_ws, size_t ws_size,
                              hipStream_t stream){
  const float* x  = (const float*)d_in[0];
  const float* Wh = (const float*)d_in[1];
  const float* bh = (const float*)d_in[2];
  const float* Wx = (const float*)d_in[3];
  const float* bx = (const float*)d_in[4];
  const float* Wo = (const float*)d_in[5];
  const float* bo = (const float*)d_in[6];
  const float* Wf = (const float*)d_in[7];
  const float* bf = (const float*)d_in[8];
  float* ws  = (float*)d_ws;
  float* out = (float*)d_out;

  hipLaunchKernelGGL(prep_kernel, dim3(1), dim3(256), 0, stream, Wh,bh,Wx,bx,Wo,bo,Wf,ws);
  hipLaunchKernelGGL(solver_kernel, dim3(NB/2), dim3(64), 0, stream,
                     x, ws+WS_WHP, ws+WS_BHX, ws+WS_BO,
                     (const f16x2*)(ws+WS_WX2), (const f16x2*)(ws+WS_WO2), (const f16x2*)(ws+WS_WF2),
                     ws+WS_OUTK, ws+WS_D2, ws+WS_F2);
  hipLaunchKernelGGL(final_kernel, dim3(NB/256), dim3(256), 0, stream,
                     ws+WS_D2, ws+WS_F2, ws+WS_OUTK, bf, out);
}